// Round 1
// baseline (465.498 us; speedup 1.0000x reference)
//
#include <hip/hip_runtime.h>
#include <cstdint>
#include <cstddef>

// ---------- types ----------
typedef __attribute__((ext_vector_type(8))) short short8;   // 8 bf16 = 4 VGPR
typedef __attribute__((ext_vector_type(4))) float floatx4;  // MFMA C/D

#define NTOK   4096
#define SHBASE 8192      // shared-expert segment base slot (2*NTOK)
#define NSLOT  12288     // 3*NTOK
#define MAT_ELEMS (1024 * 1024)

__device__ __forceinline__ unsigned short f2b(float f) {
  unsigned u = __float_as_uint(f);
  u = (u + 0x7fffu + ((u >> 16) & 1u)) >> 16;
  return (unsigned short)u;
}

// async global->LDS, 16B per lane. gsrc: per-lane address, ldst: wave-uniform base.
#define GLD16(gsrc, ldst)                                                              \
  __builtin_amdgcn_global_load_lds(                                                    \
      (const __attribute__((address_space(1))) unsigned int*)(gsrc),                   \
      (__attribute__((address_space(3))) unsigned int*)(ldst), 16, 0, 0)

// ---------- K0: bias from loop embedding, init counters ----------
__global__ void setup_kernel(const float* __restrict__ Wr,
                             const float* __restrict__ loopTable,
                             const int* __restrict__ loopIdx,
                             float* __restrict__ bias, int* __restrict__ cnt) {
  int t = threadIdx.x;
  if (t < 9) cnt[t] = (t == 8) ? NTOK : 0;
  if (t < 8) bias[t] = 0.0f;
  __syncthreads();
  const float* emb = loopTable + (size_t)(*loopIdx) * 1024;
  float partial[8] = {0, 0, 0, 0, 0, 0, 0, 0};
  for (int d = t; d < 1024; d += 256) {
    float ev = emb[d];
    const float* wr = Wr + (size_t)(1024 + d) * 8;
#pragma unroll
    for (int e = 0; e < 8; e++) partial[e] += ev * wr[e];
  }
#pragma unroll
  for (int off = 32; off > 0; off >>= 1)
#pragma unroll
    for (int e = 0; e < 8; e++) partial[e] += __shfl_xor(partial[e], off, 64);
  if ((t & 63) == 0)
#pragma unroll
    for (int e = 0; e < 8; e++) atomicAdd(&bias[e], partial[e]);
}

// ---------- K1: router (1 wave per token) + x->bf16 cast ----------
__global__ __launch_bounds__(256) void router_kernel(
    const float* __restrict__ x, const float* __restrict__ Wr,
    const float* __restrict__ bias, unsigned short* __restrict__ packedX,
    int* __restrict__ cnt, int* __restrict__ permSparse,
    float* __restrict__ wSparse, int* __restrict__ permToken,
    float* __restrict__ slotW) {
  int tok = (int)((blockIdx.x * blockDim.x + threadIdx.x) >> 6);
  int lane = threadIdx.x & 63;
  if (tok >= NTOK) return;
  const float* xr = x + (size_t)tok * 1024 + lane * 16;
  float4 v0 = ((const float4*)xr)[0];
  float4 v1 = ((const float4*)xr)[1];
  float4 v2 = ((const float4*)xr)[2];
  float4 v3 = ((const float4*)xr)[3];
  float v[16];
  v[0] = v0.x; v[1] = v0.y; v[2] = v0.z; v[3] = v0.w;
  v[4] = v1.x; v[5] = v1.y; v[6] = v1.z; v[7] = v1.w;
  v[8] = v2.x; v[9] = v2.y; v[10] = v2.z; v[11] = v2.w;
  v[12] = v3.x; v[13] = v3.y; v[14] = v3.z; v[15] = v3.w;
  // cast row into shared-expert segment of packedX
  unsigned pk[8];
#pragma unroll
  for (int j = 0; j < 8; j++)
    pk[j] = (unsigned)f2b(v[2 * j]) | ((unsigned)f2b(v[2 * j + 1]) << 16);
  uint4* dst = (uint4*)(packedX + (size_t)(SHBASE + tok) * 1024 + lane * 16);
  dst[0] = make_uint4(pk[0], pk[1], pk[2], pk[3]);
  dst[1] = make_uint4(pk[4], pk[5], pk[6], pk[7]);
  // logits (fp32, exact routing)
  float lg[8] = {0, 0, 0, 0, 0, 0, 0, 0};
#pragma unroll
  for (int j = 0; j < 16; j++) {
    float xv = v[j];
    const float4* w = (const float4*)(Wr + (size_t)(lane * 16 + j) * 8);
    float4 wa = w[0], wb = w[1];
    lg[0] += xv * wa.x; lg[1] += xv * wa.y; lg[2] += xv * wa.z; lg[3] += xv * wa.w;
    lg[4] += xv * wb.x; lg[5] += xv * wb.y; lg[6] += xv * wb.z; lg[7] += xv * wb.w;
  }
#pragma unroll
  for (int off = 32; off > 0; off >>= 1)
#pragma unroll
    for (int e = 0; e < 8; e++) lg[e] += __shfl_xor(lg[e], off, 64);
  if (lane == 0) {
    float l[8];
#pragma unroll
    for (int e = 0; e < 8; e++) l[e] = lg[e] + bias[e];
    int i0 = 0; float l0 = l[0];
#pragma unroll
    for (int e = 1; e < 8; e++) if (l[e] > l0) { l0 = l[e]; i0 = e; }
    int i1 = -1; float l1 = -1e30f;
#pragma unroll
    for (int e = 0; e < 8; e++) if (e != i0 && l[e] > l1) { l1 = l[e]; i1 = e; }
    float p0 = 1.0f / (1.0f + __expf(-l0));
    float p1 = 1.0f / (1.0f + __expf(-l1));
    int pos0 = atomicAdd(&cnt[i0], 1);
    permSparse[i0 * NTOK + pos0] = tok; wSparse[i0 * NTOK + pos0] = p0;
    int pos1 = atomicAdd(&cnt[i1], 1);
    permSparse[i1 * NTOK + pos1] = tok; wSparse[i1 * NTOK + pos1] = p1;
    permToken[SHBASE + tok] = tok; slotW[SHBASE + tok] = 1.0f;
  }
}

// ---------- K2: exclusive scan of 9 counts ----------
__global__ void scan_kernel(const int* __restrict__ cnt, int* __restrict__ offs) {
  if (threadIdx.x == 0) {
    int s = 0;
    for (int e = 0; e < 9; e++) { offs[e] = s; s += cnt[e]; }
  }
}

// ---------- K3: gather routed rows into packed layout ----------
__global__ __launch_bounds__(256) void gather_kernel(
    const int* __restrict__ cnt, const int* __restrict__ offs,
    const int* __restrict__ permSparse, const float* __restrict__ wSparse,
    unsigned short* __restrict__ packedX, int* __restrict__ permToken,
    float* __restrict__ slotW) {
  int e = blockIdx.y;
  int r = (blockIdx.x << 2) + (threadIdx.x >> 6);
  int lane = threadIdx.x & 63;
  if (r >= cnt[e]) return;
  int token = permSparse[e * NTOK + r];
  int slot = offs[e] + r;
  if (lane == 0) { permToken[slot] = token; slotW[slot] = wSparse[e * NTOK + r]; }
  const uint4* s = (const uint4*)(packedX + (size_t)(SHBASE + token) * 1024) + lane * 2;
  uint4* d = (uint4*)(packedX + (size_t)slot * 1024) + lane * 2;
  uint4 a = s[0], b = s[1];
  d[0] = a; d[1] = b;
}

// ---------- K4: transpose+cast 27 weight matrices to bf16 [out][in] ----------
// Wt layout: [27][1024][1024]; m = e (gate), 9+e (up), 18+e (down); e==8 -> shared
__global__ void transpose_cast(const float* __restrict__ Wg, const float* __restrict__ Wu,
                               const float* __restrict__ Wd, const float* __restrict__ sg,
                               const float* __restrict__ su, const float* __restrict__ sd,
                               unsigned short* __restrict__ Wt) {
  int m = blockIdx.z;
  int type = m / 9, e = m % 9;
  const float* src;
  if (type == 0)      src = (e < 8) ? Wg + (size_t)e * MAT_ELEMS : sg;
  else if (type == 1) src = (e < 8) ? Wu + (size_t)e * MAT_ELEMS : su;
  else                src = (e < 8) ? Wd + (size_t)e * MAT_ELEMS : sd;
  __shared__ float t[32][33];
  int bn = blockIdx.x << 5;  // n (out) base
  int bk = blockIdx.y << 5;  // k (in) base
  int tx = threadIdx.x, ty = threadIdx.y;
  t[ty][tx] = src[(size_t)(bk + ty) * 1024 + bn + tx];
  __syncthreads();
  Wt[(size_t)m * MAT_ELEMS + (size_t)(bn + ty) * 1024 + bk + tx] = f2b(t[tx][ty]);
}

// ---------- K5: fused gate+up GEMM + silu*up*weight -> bf16 h ----------
__global__ __launch_bounds__(256, 2) void gateup_gemm(
    const unsigned short* __restrict__ packedX, const unsigned short* __restrict__ Wt,
    const int* __restrict__ cnt, const int* __restrict__ offs,
    const float* __restrict__ slotW, unsigned short* __restrict__ Hbuf) {
  int e = blockIdx.z;
  int c = cnt[e];
  int m0 = blockIdx.y << 7;
  if (m0 >= c) return;
  int row_base = offs[e] + m0;
  int valid_m = c - m0; if (valid_m > 128) valid_m = 128;
  int n0 = blockIdx.x << 7;

  __shared__ unsigned short sA[128 * 64];
  __shared__ unsigned short sG[128 * 64];
  __shared__ unsigned short sU[128 * 64];

  int tid = threadIdx.x;
  int wv = tid >> 6, lane = tid & 63;
  int wm = wv >> 1, wn = wv & 1;

  const unsigned short* Ag = packedX + (size_t)row_base * 1024;
  const unsigned short* Gg = Wt + (size_t)e * MAT_ELEMS + (size_t)n0 * 1024;
  const unsigned short* Ug = Wt + (size_t)(9 + e) * MAT_ELEMS + (size_t)n0 * 1024;

  int srow = lane >> 3, schunk = lane & 7;

  floatx4 accG[4][4], accU[4][4];
#pragma unroll
  for (int i = 0; i < 4; i++)
#pragma unroll
    for (int j = 0; j < 4; j++) {
      accG[i][j] = floatx4{0.f, 0.f, 0.f, 0.f};
      accU[i][j] = floatx4{0.f, 0.f, 0.f, 0.f};
    }

  for (int kk = 0; kk < 1024; kk += 64) {
    __syncthreads();
#pragma unroll
    for (int j = 0; j < 4; j++) {
      int rb = (wv << 5) + (j << 3);
      size_t go = (size_t)(rb + srow) * 1024 + kk + (schunk << 3);
      GLD16(Ag + go, &sA[rb * 64]);
      GLD16(Gg + go, &sG[rb * 64]);
      GLD16(Ug + go, &sU[rb * 64]);
    }
    __syncthreads();
#pragma unroll
    for (int k0 = 0; k0 < 64; k0 += 32) {
      int aoff = ((lane >> 4) << 3) + k0;
      int arow = (wm << 6) + (lane & 15);
      short8 af[4];
#pragma unroll
      for (int mi = 0; mi < 4; mi++)
        af[mi] = *(const short8*)&sA[(arow + (mi << 4)) * 64 + aoff];
      int brow = (wn << 6) + (lane & 15);
#pragma unroll
      for (int ni = 0; ni < 4; ni++) {
        short8 gf = *(const short8*)&sG[(brow + (ni << 4)) * 64 + aoff];
        short8 uf = *(const short8*)&sU[(brow + (ni << 4)) * 64 + aoff];
#pragma unroll
        for (int mi = 0; mi < 4; mi++) {
          accG[mi][ni] = __builtin_amdgcn_mfma_f32_16x16x32_bf16(af[mi], gf, accG[mi][ni], 0, 0, 0);
          accU[mi][ni] = __builtin_amdgcn_mfma_f32_16x16x32_bf16(af[mi], uf, accU[mi][ni], 0, 0, 0);
        }
      }
    }
  }

  int colLane = lane & 15, quad = lane >> 4;
#pragma unroll
  for (int mi = 0; mi < 4; mi++) {
#pragma unroll
    for (int reg = 0; reg < 4; reg++) {
      int mrow = (wm << 6) + (mi << 4) + (quad << 2) + reg;
      if (mrow < valid_m) {
        int slot = row_base + mrow;
        float w = slotW[slot];
        unsigned short* hr = Hbuf + (size_t)slot * 1024 + n0 + (wn << 6) + colLane;
#pragma unroll
        for (int ni = 0; ni < 4; ni++) {
          float g = accG[mi][ni][reg];
          float u = accU[mi][ni][reg];
          float h = (g / (1.0f + __expf(-g))) * u * w;
          hr[ni << 4] = f2b(h);
        }
      }
    }
  }
}

// ---------- K6/K7: down projection GEMM; store (shared) or atomicAdd (routed) ----------
template <bool ATOMIC>
__global__ __launch_bounds__(256, 2) void down_gemm(
    const unsigned short* __restrict__ Hbuf, const unsigned short* __restrict__ Wt,
    const int* __restrict__ cnt, const int* __restrict__ offs,
    const int* __restrict__ permToken, float* __restrict__ out, int e_base) {
  int e = e_base + blockIdx.z;
  int c = cnt[e];
  int m0 = blockIdx.y << 7;
  if (m0 >= c) return;
  int row_base = offs[e] + m0;
  int valid_m = c - m0; if (valid_m > 128) valid_m = 128;
  int n0 = blockIdx.x << 7;

  __shared__ unsigned short sA[128 * 64];
  __shared__ unsigned short sB[128 * 64];

  int tid = threadIdx.x;
  int wv = tid >> 6, lane = tid & 63;
  int wm = wv >> 1, wn = wv & 1;

  const unsigned short* Ag = Hbuf + (size_t)row_base * 1024;
  const unsigned short* Bg = Wt + (size_t)(18 + e) * MAT_ELEMS + (size_t)n0 * 1024;

  int srow = lane >> 3, schunk = lane & 7;

  floatx4 acc[4][4];
#pragma unroll
  for (int i = 0; i < 4; i++)
#pragma unroll
    for (int j = 0; j < 4; j++) acc[i][j] = floatx4{0.f, 0.f, 0.f, 0.f};

  for (int kk = 0; kk < 1024; kk += 64) {
    __syncthreads();
#pragma unroll
    for (int j = 0; j < 4; j++) {
      int rb = (wv << 5) + (j << 3);
      size_t go = (size_t)(rb + srow) * 1024 + kk + (schunk << 3);
      GLD16(Ag + go, &sA[rb * 64]);
      GLD16(Bg + go, &sB[rb * 64]);
    }
    __syncthreads();
#pragma unroll
    for (int k0 = 0; k0 < 64; k0 += 32) {
      int aoff = ((lane >> 4) << 3) + k0;
      int arow = (wm << 6) + (lane & 15);
      short8 af[4];
#pragma unroll
      for (int mi = 0; mi < 4; mi++)
        af[mi] = *(const short8*)&sA[(arow + (mi << 4)) * 64 + aoff];
      int brow = (wn << 6) + (lane & 15);
#pragma unroll
      for (int ni = 0; ni < 4; ni++) {
        short8 bf = *(const short8*)&sB[(brow + (ni << 4)) * 64 + aoff];
#pragma unroll
        for (int mi = 0; mi < 4; mi++)
          acc[mi][ni] = __builtin_amdgcn_mfma_f32_16x16x32_bf16(af[mi], bf, acc[mi][ni], 0, 0, 0);
      }
    }
  }

  int colLane = lane & 15, quad = lane >> 4;
#pragma unroll
  for (int mi = 0; mi < 4; mi++) {
#pragma unroll
    for (int reg = 0; reg < 4; reg++) {
      int mrow = (wm << 6) + (mi << 4) + (quad << 2) + reg;
      if (mrow < valid_m) {
        int slot = row_base + mrow;
        int token = permToken[slot];
        float* orow = out + (size_t)token * 1024 + n0 + (wn << 6) + colLane;
#pragma unroll
        for (int ni = 0; ni < 4; ni++) {
          float vvv = acc[mi][ni][reg];
          if (ATOMIC) atomicAdd(&orow[ni << 4], vvv);
          else        orow[ni << 4] = vvv;
        }
      }
    }
  }
}

// ---------- launch ----------
extern "C" void kernel_launch(void* const* d_in, const int* in_sizes, int n_in,
                              void* d_out, int out_size, void* d_ws, size_t ws_size,
                              hipStream_t stream) {
  const float* x  = (const float*)d_in[0];
  const float* sg = (const float*)d_in[1];
  const float* su = (const float*)d_in[2];
  const float* sd = (const float*)d_in[3];
  const float* Wg = (const float*)d_in[4];
  const float* Wu = (const float*)d_in[5];
  const float* Wd = (const float*)d_in[6];
  const float* Wr = (const float*)d_in[7];
  const float* loopTable = (const float*)d_in[8];
  const int*   loopIdx   = (const int*)d_in[9];
  float* out = (float*)d_out;

  char* w = (char*)d_ws;
  unsigned short* Wt = (unsigned short*)w;       w += (size_t)27 * MAT_ELEMS * 2;
  unsigned short* packedX = (unsigned short*)w;  w += (size_t)NSLOT * 1024 * 2;
  unsigned short* Hbuf = (unsigned short*)w;     w += (size_t)NSLOT * 1024 * 2;
  int*   cnt        = (int*)w;   w += 16 * 4;
  int*   offs       = (int*)w;   w += 16 * 4;
  float* bias       = (float*)w; w += 16 * 4;
  int*   permSparse = (int*)w;   w += (size_t)8 * NTOK * 4;
  float* wSparse    = (float*)w; w += (size_t)8 * NTOK * 4;
  int*   permToken  = (int*)w;   w += (size_t)NSLOT * 4;
  float* slotW      = (float*)w; w += (size_t)NSLOT * 4;

  setup_kernel<<<1, 256, 0, stream>>>(Wr, loopTable, loopIdx, bias, cnt);
  router_kernel<<<1024, 256, 0, stream>>>(x, Wr, bias, packedX, cnt, permSparse,
                                          wSparse, permToken, slotW);
  scan_kernel<<<1, 64, 0, stream>>>(cnt, offs);
  gather_kernel<<<dim3(1024, 8), 256, 0, stream>>>(cnt, offs, permSparse, wSparse,
                                                   packedX, permToken, slotW);
  transpose_cast<<<dim3(32, 32, 27), dim3(32, 32), 0, stream>>>(Wg, Wu, Wd, sg, su, sd, Wt);
  gateup_gemm<<<dim3(8, 32, 9), 256, 0, stream>>>(packedX, Wt, cnt, offs, slotW, Hbuf);
  down_gemm<false><<<dim3(8, 32, 1), 256, 0, stream>>>(Hbuf, Wt, cnt, offs, permToken, out, 8);
  down_gemm<true><<<dim3(8, 32, 8), 256, 0, stream>>>(Hbuf, Wt, cnt, offs, permToken, out, 0);
}

// Round 2
// 357.270 us; speedup vs baseline: 1.3029x; 1.3029x over previous
//
#include <hip/hip_runtime.h>
#include <cstdint>
#include <cstddef>

// ---------- types ----------
typedef __attribute__((ext_vector_type(8))) short short8;   // 8 bf16 = 4 VGPR
typedef __attribute__((ext_vector_type(4))) float floatx4;  // MFMA C/D

#define NTOK   4096
#define SHBASE 8192      // shared-expert segment base slot (2*NTOK)
#define NSLOT  12288     // 3*NTOK
#define MAT_ELEMS (1024 * 1024)

__device__ __forceinline__ unsigned short f2b(float f) {
  unsigned u = __float_as_uint(f);
  u = (u + 0x7fffu + ((u >> 16) & 1u)) >> 16;
  return (unsigned short)u;
}

// async global->LDS, 16B per lane. gsrc: per-lane address, ldst: wave-uniform base.
#define GLD16(gsrc, ldst)                                                              \
  __builtin_amdgcn_global_load_lds(                                                    \
      (const __attribute__((address_space(1))) unsigned int*)(gsrc),                   \
      (__attribute__((address_space(3))) unsigned int*)(ldst), 16, 0, 0)

// ---------- K0: bias from loop embedding, init counters ----------
__global__ void setup_kernel(const float* __restrict__ Wr,
                             const float* __restrict__ loopTable,
                             const int* __restrict__ loopIdx,
                             float* __restrict__ bias, int* __restrict__ cnt) {
  int t = threadIdx.x;
  if (t < 9) cnt[t] = (t == 8) ? NTOK : 0;
  if (t < 8) bias[t] = 0.0f;
  __syncthreads();
  const float* emb = loopTable + (size_t)(*loopIdx) * 1024;
  float partial[8] = {0, 0, 0, 0, 0, 0, 0, 0};
  for (int d = t; d < 1024; d += 256) {
    float ev = emb[d];
    const float* wr = Wr + (size_t)(1024 + d) * 8;
#pragma unroll
    for (int e = 0; e < 8; e++) partial[e] += ev * wr[e];
  }
#pragma unroll
  for (int off = 32; off > 0; off >>= 1)
#pragma unroll
    for (int e = 0; e < 8; e++) partial[e] += __shfl_xor(partial[e], off, 64);
  if ((t & 63) == 0)
#pragma unroll
    for (int e = 0; e < 8; e++) atomicAdd(&bias[e], partial[e]);
}

// ---------- K1: router v2 ----------
// 64 tokens/block, 4 waves; wave w covers d in [w*256, w*256+256) with
// wave-uniform (scalar) Wr reads. LDS cross-wave reduction, per-block LDS
// slot counters, 8 global atomics per block. Also casts x rows -> bf16
// shared-expert segment of packedX (coalesced).
__global__ __launch_bounds__(256) void router_kernel(
    const float* __restrict__ x, const float* __restrict__ Wr,
    const float* __restrict__ bias, unsigned short* __restrict__ packedX,
    int* __restrict__ cnt, int* __restrict__ permSparse,
    float* __restrict__ wSparse, int* __restrict__ permToken,
    float* __restrict__ slotW) {
  int tid = threadIdx.x;
  int lane = tid & 63;
  int seg = __builtin_amdgcn_readfirstlane(tid >> 6);  // wave-uniform
  int tok0 = blockIdx.x << 6;
  int tok = tok0 + lane;

  __shared__ float red[4][64][9];
  __shared__ int lcnt[8];
  __shared__ int lbase[8];
  __shared__ int sE[64][2];
  __shared__ float sP[64][2];
  __shared__ int sPos[64][2];

  if (tid < 8) lcnt[tid] = 0;

  // logits partial: d in [seg*256, seg*256+256)
  float lg[8] = {0, 0, 0, 0, 0, 0, 0, 0};
  const float* xr = x + (size_t)tok * 1024 + seg * 256;
  const float* wr = Wr + (size_t)seg * 256 * 8;  // scalar base
  for (int i = 0; i < 256; i += 4) {
    float4 xv = *(const float4*)(xr + i);
    float xs[4] = {xv.x, xv.y, xv.z, xv.w};
#pragma unroll
    for (int r = 0; r < 4; r++) {
      const float4* w4 = (const float4*)(wr + (size_t)(i + r) * 8);
      float4 wa = w4[0], wb = w4[1];
      float xv1 = xs[r];
      lg[0] += xv1 * wa.x; lg[1] += xv1 * wa.y; lg[2] += xv1 * wa.z; lg[3] += xv1 * wa.w;
      lg[4] += xv1 * wb.x; lg[5] += xv1 * wb.y; lg[6] += xv1 * wb.z; lg[7] += xv1 * wb.w;
    }
  }
#pragma unroll
  for (int e = 0; e < 8; e++) red[seg][lane][e] = lg[e];
  __syncthreads();

  if (tid < 64) {
    float l[8];
#pragma unroll
    for (int e = 0; e < 8; e++)
      l[e] = red[0][tid][e] + red[1][tid][e] + red[2][tid][e] + red[3][tid][e] + bias[e];
    int i0 = 0; float l0 = l[0];
#pragma unroll
    for (int e = 1; e < 8; e++) if (l[e] > l0) { l0 = l[e]; i0 = e; }
    int i1 = -1; float l1 = -1e30f;
#pragma unroll
    for (int e = 0; e < 8; e++) if (e != i0 && l[e] > l1) { l1 = l[e]; i1 = e; }
    float p0 = 1.0f / (1.0f + __expf(-l0));
    float p1 = 1.0f / (1.0f + __expf(-l1));
    sE[tid][0] = i0; sP[tid][0] = p0; sPos[tid][0] = atomicAdd(&lcnt[i0], 1);
    sE[tid][1] = i1; sP[tid][1] = p1; sPos[tid][1] = atomicAdd(&lcnt[i1], 1);
    int t = tok0 + tid;
    permToken[SHBASE + t] = t;
    slotW[SHBASE + t] = 1.0f;
  }
  __syncthreads();
  if (tid < 8) lbase[tid] = atomicAdd(&cnt[tid], lcnt[tid]);
  __syncthreads();
  if (tid < 64) {
    int t = tok0 + tid;
#pragma unroll
    for (int j = 0; j < 2; j++) {
      int e = sE[tid][j];
      int pos = lbase[e] + sPos[tid][j];
      permSparse[e * NTOK + pos] = t;
      wSparse[e * NTOK + pos] = sP[tid][j];
    }
  }

  // cast 64 token rows -> bf16 shared segment (coalesced)
  const float4* xs4 = (const float4*)(x + (size_t)tok0 * 1024);
  uint2* dst = (uint2*)(packedX + (size_t)(SHBASE + tok0) * 1024);
  for (int i = tid; i < 64 * 256; i += 256) {
    float4 v = xs4[i];
    uint2 pk;
    pk.x = (unsigned)f2b(v.x) | ((unsigned)f2b(v.y) << 16);
    pk.y = (unsigned)f2b(v.z) | ((unsigned)f2b(v.w) << 16);
    dst[i] = pk;
  }
}

// ---------- K2: exclusive scan of 9 counts ----------
__global__ void scan_kernel(const int* __restrict__ cnt, int* __restrict__ offs) {
  if (threadIdx.x == 0) {
    int s = 0;
    for (int e = 0; e < 9; e++) { offs[e] = s; s += cnt[e]; }
  }
}

// ---------- K3: gather routed rows into packed layout ----------
__global__ __launch_bounds__(256) void gather_kernel(
    const int* __restrict__ cnt, const int* __restrict__ offs,
    const int* __restrict__ permSparse, const float* __restrict__ wSparse,
    unsigned short* __restrict__ packedX, int* __restrict__ permToken,
    float* __restrict__ slotW) {
  int e = blockIdx.y;
  int r = (blockIdx.x << 2) + (threadIdx.x >> 6);
  int lane = threadIdx.x & 63;
  if (r >= cnt[e]) return;
  int token = permSparse[e * NTOK + r];
  int slot = offs[e] + r;
  if (lane == 0) { permToken[slot] = token; slotW[slot] = wSparse[e * NTOK + r]; }
  const uint4* s = (const uint4*)(packedX + (size_t)(SHBASE + token) * 1024) + lane * 2;
  uint4* d = (uint4*)(packedX + (size_t)slot * 1024) + lane * 2;
  uint4 a = s[0], b = s[1];
  d[0] = a; d[1] = b;
}

// ---------- K4: transpose+cast 27 weight matrices to bf16 [out][in] ----------
// 64x64 tiles, fp32 LDS, 8B bf16 writes.
__global__ __launch_bounds__(256) void transpose_cast(
    const float* __restrict__ Wg, const float* __restrict__ Wu,
    const float* __restrict__ Wd, const float* __restrict__ sg,
    const float* __restrict__ su, const float* __restrict__ sd,
    unsigned short* __restrict__ Wt) {
  int m = blockIdx.z;
  int type = m / 9, e = m % 9;
  const float* src;
  if (type == 0)      src = (e < 8) ? Wg + (size_t)e * MAT_ELEMS : sg;
  else if (type == 1) src = (e < 8) ? Wu + (size_t)e * MAT_ELEMS : su;
  else                src = (e < 8) ? Wd + (size_t)e * MAT_ELEMS : sd;
  __shared__ float t[64][65];
  int bn = blockIdx.x << 6;  // n (out) base
  int bk = blockIdx.y << 6;  // k (in) base
  int tid = threadIdx.x;
  int ln = tid & 63, lk = tid >> 6;
#pragma unroll
  for (int i = 0; i < 16; i++) {
    int k = lk + (i << 2);
    t[k][ln] = src[(size_t)(bk + k) * 1024 + bn + ln];
  }
  __syncthreads();
  int wn = tid >> 4;          // 0..15
  int wk = (tid & 15) << 2;   // 4 bf16 per thread = 8B
  unsigned short* dstm = Wt + (size_t)m * MAT_ELEMS;
#pragma unroll
  for (int j = 0; j < 4; j++) {
    int n = wn + (j << 4);
    uint2 pk;
    pk.x = (unsigned)f2b(t[wk + 0][n]) | ((unsigned)f2b(t[wk + 1][n]) << 16);
    pk.y = (unsigned)f2b(t[wk + 2][n]) | ((unsigned)f2b(t[wk + 3][n]) << 16);
    *(uint2*)&dstm[(size_t)(bn + n) * 1024 + bk + wk] = pk;
  }
}

// ---------- K5: fused gate+up GEMM + silu*up*weight -> bf16 h ----------
__global__ __launch_bounds__(256, 2) void gateup_gemm(
    const unsigned short* __restrict__ packedX, const unsigned short* __restrict__ Wt,
    const int* __restrict__ cnt, const int* __restrict__ offs,
    const float* __restrict__ slotW, unsigned short* __restrict__ Hbuf) {
  int e = blockIdx.z;
  int c = cnt[e];
  int m0 = blockIdx.y << 7;
  if (m0 >= c) return;
  int row_base = offs[e] + m0;
  int valid_m = c - m0; if (valid_m > 128) valid_m = 128;
  int n0 = blockIdx.x << 7;

  __shared__ unsigned short sA[128 * 64];
  __shared__ unsigned short sG[128 * 64];
  __shared__ unsigned short sU[128 * 64];

  int tid = threadIdx.x;
  int wv = tid >> 6, lane = tid & 63;
  int wm = wv >> 1, wn = wv & 1;

  const unsigned short* Ag = packedX + (size_t)row_base * 1024;
  const unsigned short* Gg = Wt + (size_t)e * MAT_ELEMS + (size_t)n0 * 1024;
  const unsigned short* Ug = Wt + (size_t)(9 + e) * MAT_ELEMS + (size_t)n0 * 1024;

  int srow = lane >> 3, schunk = lane & 7;

  floatx4 accG[4][4], accU[4][4];
#pragma unroll
  for (int i = 0; i < 4; i++)
#pragma unroll
    for (int j = 0; j < 4; j++) {
      accG[i][j] = floatx4{0.f, 0.f, 0.f, 0.f};
      accU[i][j] = floatx4{0.f, 0.f, 0.f, 0.f};
    }

  for (int kk = 0; kk < 1024; kk += 64) {
    __syncthreads();
#pragma unroll
    for (int j = 0; j < 4; j++) {
      int rb = (wv << 5) + (j << 3);
      size_t go = (size_t)(rb + srow) * 1024 + kk + (schunk << 3);
      GLD16(Ag + go, &sA[rb * 64]);
      GLD16(Gg + go, &sG[rb * 64]);
      GLD16(Ug + go, &sU[rb * 64]);
    }
    __syncthreads();
#pragma unroll
    for (int k0 = 0; k0 < 64; k0 += 32) {
      int aoff = ((lane >> 4) << 3) + k0;
      int arow = (wm << 6) + (lane & 15);
      short8 af[4];
#pragma unroll
      for (int mi = 0; mi < 4; mi++)
        af[mi] = *(const short8*)&sA[(arow + (mi << 4)) * 64 + aoff];
      int brow = (wn << 6) + (lane & 15);
#pragma unroll
      for (int ni = 0; ni < 4; ni++) {
        short8 gf = *(const short8*)&sG[(brow + (ni << 4)) * 64 + aoff];
        short8 uf = *(const short8*)&sU[(brow + (ni << 4)) * 64 + aoff];
#pragma unroll
        for (int mi = 0; mi < 4; mi++) {
          accG[mi][ni] = __builtin_amdgcn_mfma_f32_16x16x32_bf16(af[mi], gf, accG[mi][ni], 0, 0, 0);
          accU[mi][ni] = __builtin_amdgcn_mfma_f32_16x16x32_bf16(af[mi], uf, accU[mi][ni], 0, 0, 0);
        }
      }
    }
  }

  int colLane = lane & 15, quad = lane >> 4;
#pragma unroll
  for (int mi = 0; mi < 4; mi++) {
#pragma unroll
    for (int reg = 0; reg < 4; reg++) {
      int mrow = (wm << 6) + (mi << 4) + (quad << 2) + reg;
      if (mrow < valid_m) {
        int slot = row_base + mrow;
        float w = slotW[slot];
        unsigned short* hr = Hbuf + (size_t)slot * 1024 + n0 + (wn << 6) + colLane;
#pragma unroll
        for (int ni = 0; ni < 4; ni++) {
          float g = accG[mi][ni][reg];
          float u = accU[mi][ni][reg];
          float h = (g / (1.0f + __expf(-g))) * u * w;
          hr[ni << 4] = f2b(h);
        }
      }
    }
  }
}

// ---------- K6/K7: down projection GEMM; store (shared) or atomicAdd (routed) ----------
template <bool ATOMIC>
__global__ __launch_bounds__(256, 2) void down_gemm(
    const unsigned short* __restrict__ Hbuf, const unsigned short* __restrict__ Wt,
    const int* __restrict__ cnt, const int* __restrict__ offs,
    const int* __restrict__ permToken, float* __restrict__ out, int e_base) {
  int e = e_base + blockIdx.z;
  int c = cnt[e];
  int m0 = blockIdx.y << 7;
  if (m0 >= c) return;
  int row_base = offs[e] + m0;
  int valid_m = c - m0; if (valid_m > 128) valid_m = 128;
  int n0 = blockIdx.x << 7;

  __shared__ unsigned short sA[128 * 64];
  __shared__ unsigned short sB[128 * 64];

  int tid = threadIdx.x;
  int wv = tid >> 6, lane = tid & 63;
  int wm = wv >> 1, wn = wv & 1;

  const unsigned short* Ag = Hbuf + (size_t)row_base * 1024;
  const unsigned short* Bg = Wt + (size_t)(18 + e) * MAT_ELEMS + (size_t)n0 * 1024;

  int srow = lane >> 3, schunk = lane & 7;

  floatx4 acc[4][4];
#pragma unroll
  for (int i = 0; i < 4; i++)
#pragma unroll
    for (int j = 0; j < 4; j++) acc[i][j] = floatx4{0.f, 0.f, 0.f, 0.f};

  for (int kk = 0; kk < 1024; kk += 64) {
    __syncthreads();
#pragma unroll
    for (int j = 0; j < 4; j++) {
      int rb = (wv << 5) + (j << 3);
      size_t go = (size_t)(rb + srow) * 1024 + kk + (schunk << 3);
      GLD16(Ag + go, &sA[rb * 64]);
      GLD16(Bg + go, &sB[rb * 64]);
    }
    __syncthreads();
#pragma unroll
    for (int k0 = 0; k0 < 64; k0 += 32) {
      int aoff = ((lane >> 4) << 3) + k0;
      int arow = (wm << 6) + (lane & 15);
      short8 af[4];
#pragma unroll
      for (int mi = 0; mi < 4; mi++)
        af[mi] = *(const short8*)&sA[(arow + (mi << 4)) * 64 + aoff];
      int brow = (wn << 6) + (lane & 15);
#pragma unroll
      for (int ni = 0; ni < 4; ni++) {
        short8 bf = *(const short8*)&sB[(brow + (ni << 4)) * 64 + aoff];
#pragma unroll
        for (int mi = 0; mi < 4; mi++)
          acc[mi][ni] = __builtin_amdgcn_mfma_f32_16x16x32_bf16(af[mi], bf, acc[mi][ni], 0, 0, 0);
      }
    }
  }

  int colLane = lane & 15, quad = lane >> 4;
#pragma unroll
  for (int mi = 0; mi < 4; mi++) {
#pragma unroll
    for (int reg = 0; reg < 4; reg++) {
      int mrow = (wm << 6) + (mi << 4) + (quad << 2) + reg;
      if (mrow < valid_m) {
        int slot = row_base + mrow;
        int token = permToken[slot];
        float* orow = out + (size_t)token * 1024 + n0 + (wn << 6) + colLane;
#pragma unroll
        for (int ni = 0; ni < 4; ni++) {
          float vvv = acc[mi][ni][reg];
          if (ATOMIC) atomicAdd(&orow[ni << 4], vvv);
          else        orow[ni << 4] = vvv;
        }
      }
    }
  }
}

// ---------- launch ----------
extern "C" void kernel_launch(void* const* d_in, const int* in_sizes, int n_in,
                              void* d_out, int out_size, void* d_ws, size_t ws_size,
                              hipStream_t stream) {
  const float* x  = (const float*)d_in[0];
  const float* sg = (const float*)d_in[1];
  const float* su = (const float*)d_in[2];
  const float* sd = (const float*)d_in[3];
  const float* Wg = (const float*)d_in[4];
  const float* Wu = (const float*)d_in[5];
  const float* Wd = (const float*)d_in[6];
  const float* Wr = (const float*)d_in[7];
  const float* loopTable = (const float*)d_in[8];
  const int*   loopIdx   = (const int*)d_in[9];
  float* out = (float*)d_out;

  char* w = (char*)d_ws;
  unsigned short* Wt = (unsigned short*)w;       w += (size_t)27 * MAT_ELEMS * 2;
  unsigned short* packedX = (unsigned short*)w;  w += (size_t)NSLOT * 1024 * 2;
  unsigned short* Hbuf = (unsigned short*)w;     w += (size_t)NSLOT * 1024 * 2;
  int*   cnt        = (int*)w;   w += 16 * 4;
  int*   offs       = (int*)w;   w += 16 * 4;
  float* bias       = (float*)w; w += 16 * 4;
  int*   permSparse = (int*)w;   w += (size_t)8 * NTOK * 4;
  float* wSparse    = (float*)w; w += (size_t)8 * NTOK * 4;
  int*   permToken  = (int*)w;   w += (size_t)NSLOT * 4;
  float* slotW      = (float*)w; w += (size_t)NSLOT * 4;

  setup_kernel<<<1, 256, 0, stream>>>(Wr, loopTable, loopIdx, bias, cnt);
  router_kernel<<<64, 256, 0, stream>>>(x, Wr, bias, packedX, cnt, permSparse,
                                        wSparse, permToken, slotW);
  scan_kernel<<<1, 64, 0, stream>>>(cnt, offs);
  gather_kernel<<<dim3(1024, 8), 256, 0, stream>>>(cnt, offs, permSparse, wSparse,
                                                   packedX, permToken, slotW);
  transpose_cast<<<dim3(16, 16, 27), 256, 0, stream>>>(Wg, Wu, Wd, sg, su, sd, Wt);
  gateup_gemm<<<dim3(8, 32, 9), 256, 0, stream>>>(packedX, Wt, cnt, offs, slotW, Hbuf);
  down_gemm<false><<<dim3(8, 32, 1), 256, 0, stream>>>(Hbuf, Wt, cnt, offs, permToken, out, 8);
  down_gemm<true><<<dim3(8, 32, 8), 256, 0, stream>>>(Hbuf, Wt, cnt, offs, permToken, out, 0);
}